// Round 2
// baseline (865.406 us; speedup 1.0000x reference)
//
#include <hip/hip_runtime.h>

// NaryDisEmbedding: out[b,f,0:128]  = counts2(x[b,f]) @ emb2   (base-2 digit histogram, 16 digits)
//                   out[b,f,128:256]= counts3(x[b,f]) @ emb3   (base-3 digit histogram, 16 digits)
// x in [0, 50000): base-2 -> popcount of low 16 bits; base-3 -> only digits 0..9 can be
// nonzero (3^10 = 59049 > 49999), digits 10..15 contribute +6 to count of digit 0.

#define B_DIM 4096
#define F_DIM 200
#define ROWS  (B_DIM * F_DIM)   // 819200
#define OUT_C 256               // 2 * EMBED_DIM

// Native clang vector type: __builtin_nontemporal_store rejects HIP_vector_type.
typedef float f32x4 __attribute__((ext_vector_type(4)));

__global__ __launch_bounds__(256, 4) void nary_embed_kernel(
    const int*   __restrict__ x,
    const float* __restrict__ emb2,
    const float* __restrict__ emb3,
    float*       __restrict__ out)
{
    const int lane = threadIdx.x & 63;
    const int wave = threadIdx.x >> 6;      // 0..3 (4 waves per block)
    const int c4   = lane * 4;              // this lane's channel quad [c4, c4+4)

    // Per-lane embedding quads, loaded once, live in registers for the whole kernel.
    // Lanes 0..31 (c4 < 128): base-2 half. Lanes 32..63: base-3 half.
    const bool is2 = (c4 < 128);
    f32x4 e0, e1, e2;
    if (is2) {
        e0 = *(const f32x4*)(emb2 + 0 * 128 + c4);
        e1 = *(const f32x4*)(emb2 + 1 * 128 + c4);
        e2 = (f32x4){0.f, 0.f, 0.f, 0.f};   // weight f2 multiplies zero for base-2 lanes
    } else {
        const int d = c4 - 128;
        e0 = *(const f32x4*)(emb3 + 0 * 128 + d);
        e1 = *(const f32x4*)(emb3 + 1 * 128 + d);
        e2 = *(const f32x4*)(emb3 + 2 * 128 + d);
    }

    // Grid-stride over rows; one wave handles one full 256-channel row (1 KB store).
    const int rowStride = gridDim.x * 4;
    for (int row = blockIdx.x * 4 + wave; row < ROWS; row += rowStride) {
        const int v = x[row];               // wave-uniform address -> 1 transaction, L1-hot

        // base-2 digit counts (16 digits)
        const int pc = __popc(v);           // v < 2^16

        // base-3 digit counts: 10 real digits; digits 10..15 are zero -> fold into c0
        int n1 = 0, n2 = 0, t = v;
        #pragma unroll
        for (int i = 0; i < 10; ++i) {
            const int q = t / 3;            // magic-multiply, no HW divide
            const int r = t - q * 3;
            n1 += (r == 1);
            n2 += (r == 2);
            t = q;
        }

        // Branch-free per-lane count selection.
        const float f0 = is2 ? (float)(16 - pc) : (float)(16 - n1 - n2);
        const float f1 = is2 ? (float)pc        : (float)n1;
        const float f2 = (float)n2;          // e2 == 0 on base-2 lanes

        f32x4 o = f0 * e0 + f1 * e1 + f2 * e2;

        // Wave writes one contiguous 1 KB row; output never re-read -> nontemporal.
        f32x4* dst = (f32x4*)(out + (size_t)row * OUT_C) + lane;
        __builtin_nontemporal_store(o, dst);
    }
}

extern "C" void kernel_launch(void* const* d_in, const int* in_sizes, int n_in,
                              void* d_out, int out_size, void* d_ws, size_t ws_size,
                              hipStream_t stream) {
    const int*   x    = (const int*)  d_in[0];
    const float* emb2 = (const float*)d_in[1];
    const float* emb3 = (const float*)d_in[2];
    float*       out  = (float*)d_out;

    // 2048 blocks x 256 threads = 8192 waves; 819200 rows / (2048*4 rows per sweep)
    // = exactly 100 iterations per wave, no tail divergence. 8 blocks/CU.
    nary_embed_kernel<<<dim3(2048), dim3(256), 0, stream>>>(x, emb2, emb3, out);
}